// Round 17
// baseline (70.927 us; speedup 1.0000x reference)
//
#include <hip/hip_runtime.h>
#include <stdint.h>

#define NP 100000
#define MP 32
#define OC 64
#define NBLK 1563                 // ceil(NP/64): one 64-pillar group per block
#define BNEPS 0.001f
#define MTOT 3200000.0
#define GIDX(i,j) ((i)*10 - (i)*((i)-1)/2 + ((j)-(i)))   // 10x10 upper-tri, 55
#define BG(a,b) B[((a)<=(b)) ? ((a)*(7-(a))/2+(b)) : ((b)*(7-(b))/2+(a))]  // 4x4 upper-tri, 10

typedef float f2 __attribute__((ext_vector_type(2)));
typedef __attribute__((address_space(3))) uint32_t as3_u32;
typedef const __attribute__((address_space(1))) uint32_t as1_u32;

// ---- 64-lane sum (DPP butterfly + swizzle + half exchange) ----
__device__ __forceinline__ float redall(float v) {
    v += __int_as_float(__builtin_amdgcn_update_dpp(0, __float_as_int(v), 0xB1,  0xF, 0xF, true));
    v += __int_as_float(__builtin_amdgcn_update_dpp(0, __float_as_int(v), 0x4E,  0xF, 0xF, true));
    v += __int_as_float(__builtin_amdgcn_update_dpp(0, __float_as_int(v), 0x141, 0xF, 0xF, true));
    v += __int_as_float(__builtin_amdgcn_update_dpp(0, __float_as_int(v), 0x140, 0xF, 0xF, true));
    v += __int_as_float(__builtin_amdgcn_ds_swizzle(__float_as_int(v), 0x401F));
    v += __shfl_xor(v, 32, 64);
    return v;
}

// ---------------------------------------------------------------------------
// Prep: folded weights. wptab[(c/2)*4+k] = f2{sgn*w2[k]}(ch c even/odd halves);
// btab[2c]={sgn*wcl[0..2], sgn*wce[0]}, btab[2c+1]={sgn*wce[1..2], sgn, 0}.
// ---------------------------------------------------------------------------
__global__ void sap_prep(const float* __restrict__ W, const float* __restrict__ gamma,
                         float* __restrict__ wptab, float4* __restrict__ btab)
{
    const int c = threadIdx.x;   // 64
    float w2[4], wcl[3], wce[3];
    w2[3] = W[3 * OC + c];
    #pragma unroll
    for (int k = 0; k < 3; ++k) {
        wcl[k] = W[(4 + k) * OC + c];
        wce[k] = W[(7 + k) * OC + c];
        w2[k]  = W[k * OC + c] + wcl[k] + wce[k];
    }
    const float sgn = (gamma[c] >= 0.0f) ? 1.0f : -1.0f;
    #pragma unroll
    for (int k = 0; k < 4; ++k)
        wptab[(((c >> 1) * 4) + k) * 2 + (c & 1)] = w2[k] * sgn;   // f2 halves
    btab[2*c]   = make_float4(wcl[0]*sgn, wcl[1]*sgn, wcl[2]*sgn, wce[0]*sgn);
    btab[2*c+1] = make_float4(wce[1]*sgn, wce[2]*sgn, sgn, 0.0f);
}

// ---------------------------------------------------------------------------
// Pass 1: LANE = PILLAR; 512 threads = 8 waves per 64-pillar block (8 channels
// per wave) for 32-waves/CU residency. Block stages its 64 pillars (32 KB)
// once via global_load_lds (inverse-XOR-swizzled source, linear dest);
// conflict-free swizzled reads feed packed-f32 channel math. NO ATOMICS:
// wave 0 writes 62 partial stats to partials[block*64+lane].
// ---------------------------------------------------------------------------
__global__ __launch_bounds__(512, 8) void sap_pass1(
    const float4* __restrict__ feat4, const int* __restrict__ nump,
    const int4* __restrict__ coors4, const f2* __restrict__ wptab,
    const float4* __restrict__ btab, float* __restrict__ hsel,
    float* __restrict__ partials)
{
    __shared__ float lds[64 * MP * 4];   // 32 KB: granule g=(pillar*32+pg) at byte g*16
    const int tid  = threadIdx.x;
    const int lane = tid & 63;
    const int swid = __builtin_amdgcn_readfirstlane(tid >> 6);   // 0..7

    // ---- stage: LDS[pillar][pg] = feat[pillar][pg ^ (pillar&31)]
    {
        const size_t blockBase = (size_t)blockIdx.x * (64 * MP);
        #pragma unroll
        for (int it = 0; it < 4; ++it) {
            const int g = it * 512 + tid;          // granule 0..2047
            const int pil = g >> 5, pg = g & 31;
            size_t se = blockBase + (size_t)(pil * MP + (pg ^ (pil & 31)));
            if (se >= (size_t)NP * MP) se = 0;     // safe pad for last block
            __builtin_amdgcn_global_load_lds((as1_u32*)(feat4 + se),
                                             (as3_u32*)(&lds[g * 4]), 16, 0, 0);
        }
    }

    // per-lane metadata while staging is in flight
    const int n = blockIdx.x * 64 + lane;
    const bool valid = n < NP;
    const int nn = valid ? n : NP - 1;
    const int cnt = valid ? nump[nn] : 0;          // coalesced
    const int4 cr = coors4[nn];                    // coalesced 16B
    const float cenz = ((float)cr.y + 0.5f) * 0.2f;
    const float ceny = ((float)cr.z + 0.5f) * 0.2f;
    const float cenx = ((float)cr.w + 0.5f) * 4.0f;

    // wave's 8 channels = 4 f2 pairs; uniform address -> scalar loads
    f2 wA[4], wB[4], wC[4], wD[4];
    #pragma unroll
    for (int j = 0; j < 4; ++j) {
        const int base = (swid * 4 + j) * 4;
        wA[j] = wptab[base];     wB[j] = wptab[base + 1];
        wC[j] = wptab[base + 2]; wD[j] = wptab[base + 3];
    }

    f2 mac[4];
    #pragma unroll
    for (int j = 0; j < 4; ++j) mac[j] = (f2){-3.0e38f, -3.0e38f};
    float S0 = 0.f, S1 = 0.f, S2 = 0.f, S3 = 0.f;
    float B[10];
    #pragma unroll
    for (int k = 0; k < 10; ++k) B[k] = 0.f;
    const bool doB = (swid == 0);

    __syncthreads();                               // staged chunk resident

    const float4* __restrict__ lp = reinterpret_cast<const float4*>(lds);
    const int gb = lane << 5;                      // this lane's pillar base granule
    const int xm = lane & 31;                      // read-side XOR (matches source)

#define POINT(FF, P) {                                                          \
    const bool act = (P) < cnt;                                                 \
    const float neg = act ? 0.0f : -3.0e38f;                                    \
    const f2 neg2 = {neg, neg};                                                 \
    const f2 fx = {(FF).x, (FF).x}, fy = {(FF).y, (FF).y};                      \
    const f2 fz = {(FF).z, (FF).z}, fw = {(FF).w, (FF).w};                      \
    _Pragma("unroll")                                                           \
    for (int j = 0; j < 4; ++j) {                                               \
        const f2 d = __builtin_elementwise_fma(fx, wA[j],                       \
                     __builtin_elementwise_fma(fy, wB[j],                       \
                     __builtin_elementwise_fma(fz, wC[j],                       \
                     __builtin_elementwise_fma(fw, wD[j], neg2))));             \
        mac[j] = __builtin_elementwise_max(mac[j], d);                          \
    }                                                                           \
    const float ax = act ? (FF).x : 0.0f, ay = act ? (FF).y : 0.0f;             \
    const float az = act ? (FF).z : 0.0f;                                       \
    S0 += ax; S1 += ay; S2 += az;                                               \
    if (doB) {                                                                  \
        const float aw = act ? (FF).w : 0.0f;                                   \
        S3 += aw;                                                               \
        B[0]=fmaf(ax,ax,B[0]); B[1]=fmaf(ax,ay,B[1]); B[2]=fmaf(ax,az,B[2]);    \
        B[3]=fmaf(ax,aw,B[3]); B[4]=fmaf(ay,ay,B[4]); B[5]=fmaf(ay,az,B[5]);    \
        B[6]=fmaf(ay,aw,B[6]); B[7]=fmaf(az,az,B[7]); B[8]=fmaf(az,aw,B[8]);    \
        B[9]=fmaf(aw,aw,B[9]);                                                  \
    } }

    {
        #pragma unroll 1
        for (int pq = 0; pq < 8; ++pq) {
            const int pb = pq * 4;
            const float4 f0 = lp[gb + ((pb + 0) ^ xm)];
            const float4 f1 = lp[gb + ((pb + 1) ^ xm)];
            const float4 f2v = lp[gb + ((pb + 2) ^ xm)];
            const float4 f3 = lp[gb + ((pb + 3) ^ xm)];
            POINT(f0, pb + 0) POINT(f1, pb + 1)
            POINT(f2v, pb + 2) POINT(f3, pb + 3)
        }
    }
#undef POINT

    // ---- epilogue: bias + floor + store (8 channels, 2x float4)
    const float fcnt = (float)cnt;
    const float rc = __builtin_amdgcn_rcpf(fmaxf(fcnt, 1.0f));
    const float mx = S0 * rc, my = S1 * rc, mz = S2 * rc;
    const float fl = (cnt < MP) ? 0.0f : -3.0e38f;
    #pragma unroll
    for (int q = 0; q < 2; ++q) {
        float o[4];
        #pragma unroll
        for (int k = 0; k < 4; ++k) {
            const int cc = q * 4 + k;
            const int c = swid * 8 + cc;
            const float4 bA = btab[2 * c];       // wcl0..2, wce0  (sgn-folded)
            const float4 bB = btab[2 * c + 1];   // wce1..2, sgn, 0
            const float bias = -(mx * bA.x + my * bA.y + mz * bA.z
                               + cenz * bA.w + ceny * bB.x + cenx * bB.y);
            const float m = (cc & 1) ? mac[cc >> 1].y : mac[cc >> 1].x;
            o[k] = bB.z * fmaxf(m + bias, fl);
        }
        if (valid)
            *reinterpret_cast<float4*>(hsel + (size_t)n * OC + swid * 8 + q * 4)
                = make_float4(o[0], o[1], o[2], o[3]);
    }

    // ---- wave 0: per-pillar Gram corrections -> 62 per-block partials
    if (doB) {
        float vals[62];
        const float Sf[4] = {S0, S1, S2, S3};
        const float mu[3] = {S0 * rc, S1 * rc, S2 * rc};
        const float ce[3] = {cenz, ceny, cenx};
        #pragma unroll
        for (int i = 0; i < 4; ++i)
            #pragma unroll
            for (int j = i; j < 4; ++j)
                vals[GIDX(i, j)] = BG(i, j);
        #pragma unroll
        for (int i = 0; i < 4; ++i)
            #pragma unroll
            for (int t = 0; t < 3; ++t)
                vals[GIDX(i, 4 + t)] = BG(i, t) - mu[t] * Sf[i];
        #pragma unroll
        for (int s = 0; s < 3; ++s)
            #pragma unroll
            for (int t = s; t < 3; ++t)
                vals[GIDX(4 + s, 4 + t)] = BG(s, t) - mu[s] * Sf[t];
        #pragma unroll
        for (int i = 0; i < 4; ++i)
            #pragma unroll
            for (int t = 0; t < 3; ++t)
                vals[GIDX(i, 7 + t)] = BG(i, t) - ce[t] * Sf[i];
        #pragma unroll
        for (int s = 0; s < 3; ++s)
            #pragma unroll
            for (int t = 0; t < 3; ++t)
                vals[GIDX(4 + s, 7 + t)] = BG(s, t) - mu[s] * Sf[t];
        #pragma unroll
        for (int s = 0; s < 3; ++s)
            #pragma unroll
            for (int t = s; t < 3; ++t)
                vals[GIDX(7 + s, 7 + t)] =
                    fmaf(fcnt * ce[s], ce[t], BG(s, t) - ce[s] * Sf[t] - ce[t] * Sf[s]);
        vals[55] = S0; vals[56] = S1; vals[57] = S2; vals[58] = S3;
        vals[59] = fmaf(-fcnt, cenz, S0);
        vals[60] = fmaf(-fcnt, ceny, S1);
        vals[61] = fmaf(-fcnt, cenx, S2);

        #pragma unroll
        for (int k = 0; k < 62; ++k) vals[k] = redall(vals[k]);
        float mine = 0.0f;
        #pragma unroll
        for (int k = 0; k < 62; ++k) mine = (lane == k) ? vals[k] : mine;
        if (lane < 62)
            partials[(size_t)blockIdx.x * 64 + lane] = mine;   // coalesced store
    }
}

// ---------------------------------------------------------------------------
// Reduce stage 1: 64 blocks; block g sums rows {g, g+64, ...} of partials.
// ---------------------------------------------------------------------------
__global__ __launch_bounds__(256) void sap_reduce1(const float* __restrict__ partials,
                                                   float* __restrict__ partials2)
{
    __shared__ float acc[4][64];
    const int k = threadIdx.x & 63, q = threadIdx.x >> 6;
    const int g = blockIdx.x;                       // 0..63
    float s = 0.0f;
    for (int b = g + 64 * q; b < NBLK; b += 256)    // ~6 rows per thread
        s += partials[(size_t)b * 64 + k];
    acc[q][k] = s;
    __syncthreads();
    if (threadIdx.x < 64)
        partials2[(size_t)g * 64 + threadIdx.x] =
            (acc[0][threadIdx.x] + acc[1][threadIdx.x]) +
            (acc[2][threadIdx.x] + acc[3][threadIdx.x]);
}

// ---------------------------------------------------------------------------
// Reduce stage 2 + finalize: sum 64 rows of partials2, fp64 Gram -> scsh.
// ---------------------------------------------------------------------------
__global__ void sap_finalize(const float* __restrict__ partials2,
                             const float* __restrict__ W,
                             const float* __restrict__ gamma,
                             const float* __restrict__ beta,
                             float* __restrict__ scsh)
{
    __shared__ float acc[4][64];
    __shared__ float stats[64];
    const int tid = threadIdx.x;          // 256
    const int k = tid & 63, q = tid >> 6;
    float s = 0.0f;
    #pragma unroll
    for (int i = 0; i < 16; ++i)
        s += partials2[(size_t)(q + 4 * i) * 64 + k];
    acc[q][k] = s;
    __syncthreads();
    if (tid < 64) stats[tid] = (acc[0][tid] + acc[1][tid]) + (acc[2][tid] + acc[3][tid]);
    __syncthreads();
    if (tid >= 64) return;
    const int c = tid;
    double G[55];
    #pragma unroll
    for (int kk = 0; kk < 55; ++kk) G[kk] = (double)stats[kk];
    double Sg[10];
    Sg[0] = (double)stats[55]; Sg[1] = (double)stats[56];
    Sg[2] = (double)stats[57]; Sg[3] = (double)stats[58];
    Sg[4] = 0.0; Sg[5] = 0.0; Sg[6] = 0.0;
    Sg[7] = (double)stats[59]; Sg[8] = (double)stats[60]; Sg[9] = (double)stats[61];
    double w[10];
    #pragma unroll
    for (int kk = 0; kk < 10; ++kk) w[kk] = (double)W[kk * OC + c];
    double sh = 0.0, qq = 0.0;
    #pragma unroll
    for (int kk = 0; kk < 10; ++kk) sh += Sg[kk] * w[kk];
    for (int i = 0; i < 10; ++i)
        for (int j = i; j < 10; ++j) {
            const double t = w[i] * w[j] * G[GIDX(i, j)];
            qq += (i == j) ? t : 2.0 * t;
        }
    const double mu_d = sh / MTOT;
    const double var_d = qq / MTOT - mu_d * mu_d;
    const float sc = gamma[c] * rsqrtf((float)var_d + BNEPS);
    scsh[c]      = sc;
    scsh[64 + c] = beta[c] - (float)mu_d * sc;
}

// ---------------------------------------------------------------------------
// Pass 2: in-place over d_out: out = relu(scale * hsel + shift).
// ---------------------------------------------------------------------------
__global__ __launch_bounds__(256) void sap_pass2(const float* __restrict__ scsh,
                                                 float* __restrict__ out)
{
    const int idx = blockIdx.x * 256 + threadIdx.x;
    if (idx >= (NP * OC) / 4) return;
    float4 h = reinterpret_cast<float4*>(out)[idx];
    const int ci = idx & 15;
    const float4 sc = reinterpret_cast<const float4*>(scsh)[ci];
    const float4 sh = reinterpret_cast<const float4*>(scsh + 64)[ci];
    float4 o;
    o.x = fmaxf(fmaf(h.x, sc.x, sh.x), 0.0f);
    o.y = fmaxf(fmaf(h.y, sc.y, sh.y), 0.0f);
    o.z = fmaxf(fmaf(h.z, sc.z, sh.z), 0.0f);
    o.w = fmaxf(fmaf(h.w, sc.w, sh.w), 0.0f);
    reinterpret_cast<float4*>(out)[idx] = o;
}

extern "C" void kernel_launch(void* const* d_in, const int* in_sizes, int n_in,
                              void* d_out, int out_size, void* d_ws, size_t ws_size,
                              hipStream_t stream) {
    const float* feat  = (const float*)d_in[0];
    const float* W     = (const float*)d_in[1];
    const float* gamma = (const float*)d_in[2];
    const float* beta  = (const float*)d_in[3];
    const int*   nump  = (const int*)d_in[4];
    const int*   coors = (const int*)d_in[5];
    float* out = (float*)d_out;

    float* wptab = (float*)d_ws;                                  // 1 KB
    float4* btab = (float4*)((char*)d_ws + 1024);                 // 2 KB
    float* scsh  = (float*)((char*)d_ws + 3072);                  // 512 B
    float* partials  = (float*)((char*)d_ws + 4096);              // 400 KB
    float* partials2 = (float*)((char*)d_ws + 4096 + 1563*64*4);  // 16 KB

    sap_prep<<<1, 64, 0, stream>>>(W, gamma, wptab, btab);
    sap_pass1<<<NBLK, 512, 0, stream>>>(
        (const float4*)feat, nump, (const int4*)coors, (const f2*)wptab,
        btab, out, partials);
    sap_reduce1<<<64, 256, 0, stream>>>(partials, partials2);
    sap_finalize<<<1, 256, 0, stream>>>(partials2, W, gamma, beta, scsh);
    sap_pass2<<<(NP * OC / 4 + 255) / 256, 256, 0, stream>>>(scsh, out);
}

// Round 18
// 59.450 us; speedup vs baseline: 1.1930x; 1.1930x over previous
//
#include <hip/hip_runtime.h>
#include <stdint.h>

#define NP 100000
#define NTASK (NP / 2)            // 50000 wave-tasks, 2 pillars each
#define MP 32
#define OC 64
#define BNEPS 0.001f
#define MTOT 3200000.0
#define PSTRIDE 144               // per-block partials: S[64] Q[64] G[10] pad

typedef short bf16x8 __attribute__((ext_vector_type(8)));   // 8 bf16 = 4 VGPRs
typedef float f32x16 __attribute__((ext_vector_type(16)));

union FRAG { uint32_t u[4]; bf16x8 v; };

// v_cvt_pk_bf16_f32: RNE-pack two fp32 -> bf16x2 (lo=src0, hi=src1)
__device__ __forceinline__ uint32_t pkbf16(float lo, float hi) {
    uint32_t r;
    asm("v_cvt_pk_bf16_f32 %0, %1, %2" : "=v"(r) : "v"(lo), "v"(hi));
    return r;
}

// 32-lane sum butterfly (DPP + swizzle). Every lane of each half holds the sum.
__device__ __forceinline__ float red32(float v) {
    v += __int_as_float(__builtin_amdgcn_update_dpp(0, __float_as_int(v), 0xB1,  0xF, 0xF, true));
    v += __int_as_float(__builtin_amdgcn_update_dpp(0, __float_as_int(v), 0x4E,  0xF, 0xF, true));
    v += __int_as_float(__builtin_amdgcn_update_dpp(0, __float_as_int(v), 0x141, 0xF, 0xF, true));
    v += __int_as_float(__builtin_amdgcn_update_dpp(0, __float_as_int(v), 0x140, 0xF, 0xF, true));
    v += __int_as_float(__builtin_amdgcn_ds_swizzle(__float_as_int(v), 0x401F));
    return v;
}

__device__ __forceinline__ float max16(f32x16 d) {
    const float a = fmaxf(fmaxf(d[0], d[1]),  fmaxf(d[2], d[3]));
    const float b = fmaxf(fmaxf(d[4], d[5]),  fmaxf(d[6], d[7]));
    const float c = fmaxf(fmaxf(d[8], d[9]),  fmaxf(d[10], d[11]));
    const float e = fmaxf(fmaxf(d[12], d[13]), fmaxf(d[14], d[15]));
    return fmaxf(fmaxf(a, b), fmaxf(c, e));
}

// ---------------------------------------------------------------------------
// Pass 1 (r8 MFMA body, atomic-free ending): wave-task = 2 pillars.
// lane = point|pillar-half for loads, lane = channel for outputs.
// d' = f.w2' via mfma_32x32x16_bf16 (K=4 zero-padded, masked rows -> C=-3e38).
// Per-pillar sums via DPP butterfly. Sigma d'^2 via global raw 4x4 Gram
// (per-lane accumulators, quadratic form applied in finalize).
// Ending: block-reduce S/Q/G -> partials[block][144] coalesced store.
// ---------------------------------------------------------------------------
__global__ __launch_bounds__(256) void sap_pass1(
    const float* __restrict__ feat, const float* __restrict__ W,
    const float* __restrict__ gamma, const int* __restrict__ nump,
    const int* __restrict__ coors, float* __restrict__ hsel,
    float* __restrict__ partials, const int nwaves)
{
    __shared__ float sred[4][128];
    __shared__ float sredG[4][10];
    const int lane = threadIdx.x & 63;
    const int wid  = threadIdx.x >> 6;
    const int c = lane;
    const int pi = lane & 31;
    const bool hiHalf = lane >= 32;

    // W is (10,64) row-major. Fold cluster/center: W2 = W[k] + W[4+k] + W[7+k].
    float w2[4], wcl[3], wce[3];
    w2[3] = W[3 * OC + c];
    #pragma unroll
    for (int k = 0; k < 3; ++k) {
        wcl[k] = W[(4 + k) * OC + c];
        wce[k] = W[(7 + k) * OC + c];
        w2[k]  = W[k * OC + c] + wcl[k] + wce[k];
    }
    const float sgn = (gamma[c] >= 0.0f) ? 1.0f : -1.0f;
    #pragma unroll
    for (int k = 0; k < 3; ++k) { wcl[k] *= sgn; wce[k] *= sgn; w2[k] *= sgn; }
    w2[3] *= sgn;

    // Loop-invariant B fragments (w2', bf16). B[k][n]: col=lane&31, lanes<32
    // hold k0..7 (k0-3 = data), lanes>=32 hold k8..15 = zero.
    const uint32_t bw0 = pkbf16(w2[0], w2[1]);
    const uint32_t bw1 = pkbf16(w2[2], w2[3]);
    const uint32_t ob0 = (uint32_t)__shfl_xor((int)bw0, 32, 64);
    const uint32_t ob1 = (uint32_t)__shfl_xor((int)bw1, 32, 64);
    FRAG B0, B1;                                   // channels 0-31 / 32-63
    B0.u[0] = hiHalf ? 0u : bw0; B0.u[1] = hiHalf ? 0u : bw1; B0.u[2] = 0u; B0.u[3] = 0u;
    B1.u[0] = hiHalf ? 0u : ob0; B1.u[1] = hiHalf ? 0u : ob1; B1.u[2] = 0u; B1.u[3] = 0u;

    const float4* __restrict__ feat4 = reinterpret_cast<const float4*>(feat);

    float accS = 0.0f, accQ = 0.0f;
    float g0=0.f,g1=0.f,g2=0.f,g3=0.f,g4=0.f,g5=0.f,g6=0.f,g7=0.f,g8=0.f,g9=0.f;

    int t = blockIdx.x * 4 + wid;                  // always < NTASK at start
    float4 curv = feat4[(size_t)t * 64 + lane];

    for (; t < NTASK; t += nwaves) {
        const int tu = __builtin_amdgcn_readfirstlane(t);
        const int tn = t + nwaves;
        float4 nxtv = curv;
        if (tn < NTASK) nxtv = feat4[(size_t)tn * 64 + lane];   // prefetch

        const int nA = 2 * tu, nB = nA + 1;
        const int cntA = nump[nA], cntB = nump[nB];             // uniform s_load
        const int izA = coors[4*nA+1], iyA = coors[4*nA+2], ixA = coors[4*nA+3];
        const int izB = coors[4*nB+1], iyB = coors[4*nB+2], ixB = coors[4*nB+3];

        // mask this lane's point
        const int  myCnt = hiHalf ? cntB : cntA;
        const bool act = pi < myCnt;
        const float mx = act ? curv.x : 0.0f, my = act ? curv.y : 0.0f;
        const float mz = act ? curv.z : 0.0f, mw = act ? curv.w : 0.0f;

        // global raw 4x4 Gram (per-lane, reduced once at kernel end)
        g0 = fmaf(mx, mx, g0); g1 = fmaf(my, my, g1); g2 = fmaf(mz, mz, g2);
        g3 = fmaf(mw, mw, g3); g4 = fmaf(mx, my, g4); g5 = fmaf(mx, mz, g5);
        g6 = fmaf(mx, mw, g6); g7 = fmaf(my, mz, g7); g8 = fmaf(my, mw, g8);
        g9 = fmaf(mz, mw, g9);

        // per-pillar feature sums (DPP butterfly within halves, then exchange)
        float s0 = red32(mx), s1 = red32(my), s2 = red32(mz), s3 = red32(mw);
        const float o0 = __shfl_xor(s0, 32, 64), o1 = __shfl_xor(s1, 32, 64);
        const float o2 = __shfl_xor(s2, 32, 64), o3 = __shfl_xor(s3, 32, 64);
        const float SA0 = hiHalf ? o0 : s0, SA1 = hiHalf ? o1 : s1;
        const float SA2 = hiHalf ? o2 : s2, SA3 = hiHalf ? o3 : s3;
        const float SB0 = hiHalf ? s0 : o0, SB1 = hiHalf ? s1 : o1;
        const float SB2 = hiHalf ? s2 : o2, SB3 = hiHalf ? s3 : o3;

        // A fragments: A[p][k], row=lane&31 (=point), lanes<32 k0..7, hi k8..15=0
        const uint32_t pk0 = pkbf16(mx, my), pk1 = pkbf16(mz, mw);
        const uint32_t qk0 = (uint32_t)__shfl_xor((int)pk0, 32, 64);
        const uint32_t qk1 = (uint32_t)__shfl_xor((int)pk1, 32, 64);
        FRAG AA, AB;
        AA.u[0] = hiHalf ? 0u : pk0; AA.u[1] = hiHalf ? 0u : pk1; AA.u[2] = 0u; AA.u[3] = 0u;
        AB.u[0] = hiHalf ? 0u : qk0; AB.u[1] = hiHalf ? 0u : qk1; AB.u[2] = 0u; AB.u[3] = 0u;

        // C masks: row = (reg&3) + 8*(reg>>2) + 4*(lane>>5); masked rows -> -3e38
        f32x16 CA, CB;
        #pragma unroll
        for (int r = 0; r < 16; ++r) {
            const int row = (r & 3) + 8 * (r >> 2) + (hiHalf ? 4 : 0);
            CA[r] = (row < cntA) ? 0.0f : -3.0e38f;
            CB[r] = (row < cntB) ? 0.0f : -3.0e38f;
        }

        f32x16 D;
        D = __builtin_amdgcn_mfma_f32_32x32x16_bf16(AA.v, B0.v, CA, 0, 0, 0);
        float mA0 = max16(D);
        D = __builtin_amdgcn_mfma_f32_32x32x16_bf16(AA.v, B1.v, CA, 0, 0, 0);
        float mA1 = max16(D);
        D = __builtin_amdgcn_mfma_f32_32x32x16_bf16(AB.v, B0.v, CB, 0, 0, 0);
        float mB0 = max16(D);
        D = __builtin_amdgcn_mfma_f32_32x32x16_bf16(AB.v, B1.v, CB, 0, 0, 0);
        float mB1 = max16(D);

        // combine point-halves; select channel tile (D col = lane&31)
        mA0 = fmaxf(mA0, __shfl_xor(mA0, 32, 64));
        mA1 = fmaxf(mA1, __shfl_xor(mA1, 32, 64));
        mB0 = fmaxf(mB0, __shfl_xor(mB0, 32, 64));
        mB1 = fmaxf(mB1, __shfl_xor(mB1, 32, 64));
        const float mA = hiHalf ? mA1 : mA0;   // max d' for channel=lane, pillar A
        const float mB = hiHalf ? mB1 : mB0;

        // epilogue pillar A
        {
            const float fcnt = (float)cntA, rc = __builtin_amdgcn_rcpf(fcnt);
            const float cz = ((float)izA + 0.5f) * 0.2f;
            const float cy = ((float)iyA + 0.5f) * 0.2f;
            const float cx = ((float)ixA + 0.5f) * 4.0f;
            const float mt   = fmaf(SA2, wcl[2], fmaf(SA1, wcl[1], SA0 * wcl[0]));
            const float bias = -fmaf(mt, rc, fmaf(cz, wce[0], fmaf(cy, wce[1], cx * wce[2])));
            const float ssum = fmaf(SA3, w2[3], fmaf(SA2, w2[2], fmaf(SA1, w2[1], SA0 * w2[0])));
            float hm = mA + bias;
            if (cntA < MP) hm = fmaxf(hm, 0.0f);
            hsel[(size_t)nA * OC + c] = sgn * hm;
            const float fb = fcnt * bias;
            accS = fmaf(sgn, ssum + fb, accS);
            accQ += fmaf(fb, bias, (bias + bias) * ssum);
        }
        // epilogue pillar B
        {
            const float fcnt = (float)cntB, rc = __builtin_amdgcn_rcpf(fcnt);
            const float cz = ((float)izB + 0.5f) * 0.2f;
            const float cy = ((float)iyB + 0.5f) * 0.2f;
            const float cx = ((float)ixB + 0.5f) * 4.0f;
            const float mt   = fmaf(SB2, wcl[2], fmaf(SB1, wcl[1], SB0 * wcl[0]));
            const float bias = -fmaf(mt, rc, fmaf(cz, wce[0], fmaf(cy, wce[1], cx * wce[2])));
            const float ssum = fmaf(SB3, w2[3], fmaf(SB2, w2[2], fmaf(SB1, w2[1], SB0 * w2[0])));
            float hm = mB + bias;
            if (cntB < MP) hm = fmaxf(hm, 0.0f);
            hsel[(size_t)nB * OC + c] = sgn * hm;
            const float fb = fcnt * bias;
            accS = fmaf(sgn, ssum + fb, accS);
            accQ += fmaf(fb, bias, (bias + bias) * ssum);
        }
        curv = nxtv;
    }

    // ---- final block reduction -> coalesced partials store (NO atomics)
    sred[wid][c]      = accS;
    sred[wid][64 + c] = accQ;
    g0 = red32(g0); g0 += __shfl_xor(g0, 32, 64);
    g1 = red32(g1); g1 += __shfl_xor(g1, 32, 64);
    g2 = red32(g2); g2 += __shfl_xor(g2, 32, 64);
    g3 = red32(g3); g3 += __shfl_xor(g3, 32, 64);
    g4 = red32(g4); g4 += __shfl_xor(g4, 32, 64);
    g5 = red32(g5); g5 += __shfl_xor(g5, 32, 64);
    g6 = red32(g6); g6 += __shfl_xor(g6, 32, 64);
    g7 = red32(g7); g7 += __shfl_xor(g7, 32, 64);
    g8 = red32(g8); g8 += __shfl_xor(g8, 32, 64);
    g9 = red32(g9); g9 += __shfl_xor(g9, 32, 64);
    if (lane == 0) {
        sredG[wid][0] = g0; sredG[wid][1] = g1; sredG[wid][2] = g2;
        sredG[wid][3] = g3; sredG[wid][4] = g4; sredG[wid][5] = g5;
        sredG[wid][6] = g6; sredG[wid][7] = g7; sredG[wid][8] = g8;
        sredG[wid][9] = g9;
    }
    __syncthreads();
    if (wid == 0) {
        float* row = partials + (size_t)blockIdx.x * PSTRIDE;
        row[lane]      = sred[0][lane] + sred[1][lane] + sred[2][lane] + sred[3][lane];
        row[64 + lane] = sred[0][64+lane] + sred[1][64+lane] + sred[2][64+lane] + sred[3][64+lane];
        if (lane < 10)
            row[128 + lane] = sredG[0][lane] + sredG[1][lane] + sredG[2][lane] + sredG[3][lane];
        if (lane >= 10 && lane < 16) row[128 + lane] = 0.0f;
    }
}

// ---------------------------------------------------------------------------
// Reduce stage 1: 64 blocks; block g sums rows {g, g+64, ...} of partials.
// Fixed order -> deterministic.
// ---------------------------------------------------------------------------
__global__ __launch_bounds__(256) void sap_reduce1(const float* __restrict__ partials,
                                                   float* __restrict__ partials2,
                                                   const int nrows)
{
    const int col = threadIdx.x;
    if (col >= PSTRIDE) return;
    const int g = blockIdx.x;                       // 0..63
    float s = 0.0f;
    for (int b = g; b < nrows; b += 64)
        s += partials[(size_t)b * PSTRIDE + col];
    partials2[(size_t)g * PSTRIDE + col] = s;
}

// ---------------------------------------------------------------------------
// Reduce stage 2 + finalize: sum 64 rows, fp64 BN stats -> scsh.
// mu[c] = S[c]/M; var[c] = (w^T G w + Q[c])/M - mu^2  (w = folded W col).
// ---------------------------------------------------------------------------
__global__ void sap_finalize(const float* __restrict__ partials2,
                             const float* __restrict__ W,
                             const float* __restrict__ gamma,
                             const float* __restrict__ beta,
                             float* __restrict__ scsh)
{
    __shared__ float stats[PSTRIDE];
    const int tid = threadIdx.x;          // 256
    if (tid < PSTRIDE) {
        float s = 0.0f;
        #pragma unroll
        for (int b = 0; b < 64; ++b)
            s += partials2[(size_t)b * PSTRIDE + tid];
        stats[tid] = s;
    }
    __syncthreads();
    if (tid >= 64) return;
    const int c = tid;
    double G[10];
    #pragma unroll
    for (int k = 0; k < 10; ++k) G[k] = (double)stats[128 + k];
    double w[4];
    w[3] = (double)W[3 * OC + c];
    #pragma unroll
    for (int k = 0; k < 3; ++k)
        w[k] = (double)W[k * OC + c] + (double)W[(4 + k) * OC + c] + (double)W[(7 + k) * OC + c];
    const double q = w[0]*w[0]*G[0] + w[1]*w[1]*G[1] + w[2]*w[2]*G[2] + w[3]*w[3]*G[3]
        + 2.0 * (w[0]*w[1]*G[4] + w[0]*w[2]*G[5] + w[0]*w[3]*G[6]
               + w[1]*w[2]*G[7] + w[1]*w[3]*G[8] + w[2]*w[3]*G[9]);
    const double S  = (double)stats[c];
    const double Qb = (double)stats[64 + c];
    const double mu_d  = S / MTOT;
    const double var_d = (q + Qb) / MTOT - mu_d * mu_d;
    const float sc = gamma[c] * rsqrtf((float)var_d + BNEPS);
    scsh[c]      = sc;
    scsh[64 + c] = beta[c] - (float)mu_d * sc;
}

// ---------------------------------------------------------------------------
// Pass 2: in-place over d_out: out = relu(scale * hsel + shift).
// ---------------------------------------------------------------------------
__global__ __launch_bounds__(256) void sap_pass2(const float* __restrict__ scsh,
                                                 float* __restrict__ out)
{
    const int idx = blockIdx.x * 256 + threadIdx.x;
    if (idx >= (NP * OC) / 4) return;
    float4 h = reinterpret_cast<float4*>(out)[idx];
    const int ci = idx & 15;
    const float4 sc = reinterpret_cast<const float4*>(scsh)[ci];
    const float4 sh = reinterpret_cast<const float4*>(scsh + 64)[ci];
    float4 o;
    o.x = fmaxf(fmaf(h.x, sc.x, sh.x), 0.0f);
    o.y = fmaxf(fmaf(h.y, sc.y, sh.y), 0.0f);
    o.z = fmaxf(fmaf(h.z, sc.z, sh.z), 0.0f);
    o.w = fmaxf(fmaf(h.w, sc.w, sh.w), 0.0f);
    reinterpret_cast<float4*>(out)[idx] = o;
}

extern "C" void kernel_launch(void* const* d_in, const int* in_sizes, int n_in,
                              void* d_out, int out_size, void* d_ws, size_t ws_size,
                              hipStream_t stream) {
    const float* feat  = (const float*)d_in[0];
    const float* W     = (const float*)d_in[1];
    const float* gamma = (const float*)d_in[2];
    const float* beta  = (const float*)d_in[3];
    const int*   nump  = (const int*)d_in[4];
    const int*   coors = (const int*)d_in[5];
    float* out = (float*)d_out;

    // pick grid1 to fit partials in d_ws (deterministic given fixed ws_size)
    int grid1 = 2048;
    const size_t fixed = 64 * PSTRIDE * 4 + 512;   // partials2 + scsh
    while (grid1 > 256 && (size_t)grid1 * PSTRIDE * 4 + fixed > ws_size)
        grid1 >>= 1;

    float* partials  = (float*)d_ws;                                   // grid1*144*4
    float* partials2 = partials + (size_t)grid1 * PSTRIDE;             // 64*144*4
    float* scsh      = partials2 + 64 * PSTRIDE;                       // 512 B

    sap_pass1<<<grid1, 256, 0, stream>>>(
        feat, W, gamma, nump, coors, out, partials, grid1 * 4);
    sap_reduce1<<<64, 256, 0, stream>>>(partials, partials2, grid1);
    sap_finalize<<<1, 256, 0, stream>>>(partials2, W, gamma, beta, scsh);
    sap_pass2<<<(NP * OC / 4 + 255) / 256, 256, 0, stream>>>(scsh, out);
}

// Round 19
// 53.097 us; speedup vs baseline: 1.3358x; 1.1197x over previous
//
#include <hip/hip_runtime.h>
#include <stdint.h>

#define NP 100000
#define NTASK (NP / 2)            // 50000 wave-tasks, 2 pillars each
#define MP 32
#define OC 64
#define BNEPS 0.001f
#define MTOT 3200000.0
#define PSTRIDE 144               // per-block partials: S[64] Q[64] G[10] pad

typedef short bf16x8 __attribute__((ext_vector_type(8)));   // 8 bf16 = 4 VGPRs
typedef float f32x16 __attribute__((ext_vector_type(16)));

union FRAG { uint32_t u[4]; bf16x8 v; };

// v_cvt_pk_bf16_f32: RNE-pack two fp32 -> bf16x2 (lo=src0, hi=src1)
__device__ __forceinline__ uint32_t pkbf16(float lo, float hi) {
    uint32_t r;
    asm("v_cvt_pk_bf16_f32 %0, %1, %2" : "=v"(r) : "v"(lo), "v"(hi));
    return r;
}

// Split fp32 bias into bf16 hi + bf16 lo residual, packed (k4=hi, k5=lo).
// hi exactly representable in bf16 -> repack is exact; |err| ~ 2^-17 * |b|.
__device__ __forceinline__ uint32_t biasPack(float b) {
    const uint32_t h = pkbf16(b, b) & 0xFFFFu;
    const float hf = __int_as_float(h << 16);
    return pkbf16(hf, b - hf);
}

// 32-lane sum butterfly (DPP + swizzle). Every lane of each half holds the sum.
__device__ __forceinline__ float red32(float v) {
    v += __int_as_float(__builtin_amdgcn_update_dpp(0, __float_as_int(v), 0xB1,  0xF, 0xF, true));
    v += __int_as_float(__builtin_amdgcn_update_dpp(0, __float_as_int(v), 0x4E,  0xF, 0xF, true));
    v += __int_as_float(__builtin_amdgcn_update_dpp(0, __float_as_int(v), 0x141, 0xF, 0xF, true));
    v += __int_as_float(__builtin_amdgcn_update_dpp(0, __float_as_int(v), 0x140, 0xF, 0xF, true));
    v += __int_as_float(__builtin_amdgcn_ds_swizzle(__float_as_int(v), 0x401F));
    return v;
}

// nested triples -> v_max3_f32 fusion (8 ops)
__device__ __forceinline__ float max16(f32x16 d) {
    const float m0 = fmaxf(fmaxf(d[0], d[1]), d[2]);
    const float m1 = fmaxf(fmaxf(d[3], d[4]), d[5]);
    const float m2 = fmaxf(fmaxf(d[6], d[7]), d[8]);
    const float m3 = fmaxf(fmaxf(d[9], d[10]), d[11]);
    const float m4 = fmaxf(fmaxf(d[12], d[13]), d[14]);
    const float m5 = fmaxf(fmaxf(m0, m1), d[15]);
    const float m6 = fmaxf(fmaxf(m2, m3), m4);
    return fmaxf(m5, m6);
}

// ---------------------------------------------------------------------------
// Pass 1: wave-task = 2 pillars. d'+bias computed ENTIRELY inside the MFMA:
// K0-3 = f.w2', K4/K5 = act * (bias_hi + bias_lo). Masked rows give D=0 =
// the reference's masked-h semantics, so NO C-mask and NO epilogue floor.
// hsel = sgn * max_rows(D). Stats: per-pillar sums via DPP butterfly; Sigma
// d'^2 via global raw 4x4 Gram + per-pillar bias corrections (fp32).
// Ending: block-reduce -> partials[block][144] coalesced store (no atomics).
// ---------------------------------------------------------------------------
__global__ __launch_bounds__(256) void sap_pass1(
    const float* __restrict__ feat, const float* __restrict__ W,
    const float* __restrict__ gamma, const int* __restrict__ nump,
    const int* __restrict__ coors, float* __restrict__ hsel,
    float* __restrict__ partials, const int nwaves)
{
    __shared__ float sred[4][128];
    __shared__ float sredG[4][10];
    const int lane = threadIdx.x & 63;
    const int wid  = threadIdx.x >> 6;
    const int c = lane;
    const int pi = lane & 31;
    const bool hiHalf = lane >= 32;

    // W is (10,64) row-major. Fold cluster/center: W2 = W[k] + W[4+k] + W[7+k].
    float w2[4], wcl[3], wce[3];
    w2[3] = W[3 * OC + c];
    #pragma unroll
    for (int k = 0; k < 3; ++k) {
        wcl[k] = W[(4 + k) * OC + c];
        wce[k] = W[(7 + k) * OC + c];
        w2[k]  = W[k * OC + c] + wcl[k] + wce[k];
    }
    const float sgn = (gamma[c] >= 0.0f) ? 1.0f : -1.0f;
    #pragma unroll
    for (int k = 0; k < 3; ++k) { wcl[k] *= sgn; wce[k] *= sgn; w2[k] *= sgn; }
    w2[3] *= sgn;

    // Loop-invariant w2' halves of B fragments (k0..3). k4/k5 vary per task.
    const uint32_t bw0 = pkbf16(w2[0], w2[1]);
    const uint32_t bw1 = pkbf16(w2[2], w2[3]);
    const uint32_t ob0 = (uint32_t)__shfl_xor((int)bw0, 32, 64);
    const uint32_t ob1 = (uint32_t)__shfl_xor((int)bw1, 32, 64);
    const uint32_t B0u0 = hiHalf ? 0u : bw0, B0u1 = hiHalf ? 0u : bw1;
    const uint32_t B1u0 = hiHalf ? 0u : ob0, B1u1 = hiHalf ? 0u : ob1;

    const float4* __restrict__ feat4 = reinterpret_cast<const float4*>(feat);

    float accS = 0.0f, accQ = 0.0f;
    float g0=0.f,g1=0.f,g2=0.f,g3=0.f,g4=0.f,g5=0.f,g6=0.f,g7=0.f,g8=0.f,g9=0.f;

    int t = blockIdx.x * 4 + wid;                  // always < NTASK at start
    float4 curv = feat4[(size_t)t * 64 + lane];

    for (; t < NTASK; t += nwaves) {
        const int tu = __builtin_amdgcn_readfirstlane(t);
        const int tn = t + nwaves;
        float4 nxtv = curv;
        if (tn < NTASK) nxtv = feat4[(size_t)tn * 64 + lane];   // prefetch

        const int nA = 2 * tu, nB = nA + 1;
        const int cntA = nump[nA], cntB = nump[nB];             // uniform s_load
        const int izA = coors[4*nA+1], iyA = coors[4*nA+2], ixA = coors[4*nA+3];
        const int izB = coors[4*nB+1], iyB = coors[4*nB+2], ixB = coors[4*nB+3];

        // mask this lane's point (pillar = half)
        const int  myCnt = hiHalf ? cntB : cntA;
        const bool act = pi < myCnt;
        const float mx = act ? curv.x : 0.0f, my = act ? curv.y : 0.0f;
        const float mz = act ? curv.z : 0.0f, mw = act ? curv.w : 0.0f;

        // global raw 4x4 Gram (per-lane, reduced once at kernel end)
        g0 = fmaf(mx, mx, g0); g1 = fmaf(my, my, g1); g2 = fmaf(mz, mz, g2);
        g3 = fmaf(mw, mw, g3); g4 = fmaf(mx, my, g4); g5 = fmaf(mx, mz, g5);
        g6 = fmaf(mx, mw, g6); g7 = fmaf(my, mz, g7); g8 = fmaf(my, mw, g8);
        g9 = fmaf(mz, mw, g9);

        // per-pillar feature sums (DPP butterfly within halves, then exchange)
        float s0 = red32(mx), s1 = red32(my), s2 = red32(mz), s3 = red32(mw);
        const float o0 = __shfl_xor(s0, 32, 64), o1 = __shfl_xor(s1, 32, 64);
        const float o2 = __shfl_xor(s2, 32, 64), o3 = __shfl_xor(s3, 32, 64);
        const float SA0 = hiHalf ? o0 : s0, SA1 = hiHalf ? o1 : s1;
        const float SA2 = hiHalf ? o2 : s2, SA3 = hiHalf ? o3 : s3;
        const float SB0 = hiHalf ? s0 : o0, SB1 = hiHalf ? s1 : o1;
        const float SB2 = hiHalf ? s2 : o2, SB3 = hiHalf ? s3 : o3;

        // per-channel biases (fp32, lane = channel) for both pillars
        const float fcA = (float)cntA, rcA = __builtin_amdgcn_rcpf(fcA);
        const float fcB = (float)cntB, rcB = __builtin_amdgcn_rcpf(fcB);
        const float czA = ((float)izA + 0.5f) * 0.2f;
        const float cyA = ((float)iyA + 0.5f) * 0.2f;
        const float cxA = ((float)ixA + 0.5f) * 4.0f;
        const float czB = ((float)izB + 0.5f) * 0.2f;
        const float cyB = ((float)iyB + 0.5f) * 0.2f;
        const float cxB = ((float)ixB + 0.5f) * 4.0f;
        const float mtA   = fmaf(SA2, wcl[2], fmaf(SA1, wcl[1], SA0 * wcl[0]));
        const float biasA = -fmaf(mtA, rcA, fmaf(czA, wce[0], fmaf(cyA, wce[1], cxA * wce[2])));
        const float mtB   = fmaf(SB2, wcl[2], fmaf(SB1, wcl[1], SB0 * wcl[0]));
        const float biasB = -fmaf(mtB, rcB, fmaf(czB, wce[0], fmaf(cyB, wce[1], cxB * wce[2])));

        // bias -> (k4,k5) bf16 hi/lo; route channel tiles
        const uint32_t pkA = biasPack(biasA);
        const uint32_t pkB = biasPack(biasB);
        const uint32_t pkAo = (uint32_t)__shfl_xor((int)pkA, 32, 64);
        const uint32_t pkBo = (uint32_t)__shfl_xor((int)pkB, 32, 64);

        // A fragments: rows = points; k4/k5 = act ? 1 : 0
        const uint32_t one2 = act ? 0x3F803F80u : 0u;
        const uint32_t one2o = (uint32_t)__shfl_xor((int)one2, 32, 64);
        const uint32_t pk0 = pkbf16(mx, my), pk1 = pkbf16(mz, mw);
        const uint32_t qk0 = (uint32_t)__shfl_xor((int)pk0, 32, 64);
        const uint32_t qk1 = (uint32_t)__shfl_xor((int)pk1, 32, 64);
        FRAG AA, AB;
        AA.u[0] = hiHalf ? 0u : pk0; AA.u[1] = hiHalf ? 0u : pk1;
        AA.u[2] = hiHalf ? 0u : one2; AA.u[3] = 0u;
        AB.u[0] = hiHalf ? 0u : qk0; AB.u[1] = hiHalf ? 0u : qk1;
        AB.u[2] = hiHalf ? 0u : one2o; AB.u[3] = 0u;

        // B fragments per (pillar, channel-tile)
        FRAG B0A, B1A, B0B, B1B;
        B0A.u[0] = B0u0; B0A.u[1] = B0u1; B0A.u[2] = hiHalf ? 0u : pkA;  B0A.u[3] = 0u;
        B1A.u[0] = B1u0; B1A.u[1] = B1u1; B1A.u[2] = hiHalf ? 0u : pkAo; B1A.u[3] = 0u;
        B0B.u[0] = B0u0; B0B.u[1] = B0u1; B0B.u[2] = hiHalf ? 0u : pkB;  B0B.u[3] = 0u;
        B1B.u[0] = B1u0; B1B.u[1] = B1u1; B1B.u[2] = hiHalf ? 0u : pkBo; B1B.u[3] = 0u;

        const f32x16 CZ = {};
        f32x16 D;
        D = __builtin_amdgcn_mfma_f32_32x32x16_bf16(AA.v, B0A.v, CZ, 0, 0, 0);
        float mA0 = max16(D);
        D = __builtin_amdgcn_mfma_f32_32x32x16_bf16(AA.v, B1A.v, CZ, 0, 0, 0);
        float mA1 = max16(D);
        D = __builtin_amdgcn_mfma_f32_32x32x16_bf16(AB.v, B0B.v, CZ, 0, 0, 0);
        float mB0 = max16(D);
        D = __builtin_amdgcn_mfma_f32_32x32x16_bf16(AB.v, B1B.v, CZ, 0, 0, 0);
        float mB1 = max16(D);

        // combine point-halves; select channel tile (D col = lane&31)
        mA0 = fmaxf(mA0, __shfl_xor(mA0, 32, 64));
        mA1 = fmaxf(mA1, __shfl_xor(mA1, 32, 64));
        mB0 = fmaxf(mB0, __shfl_xor(mB0, 32, 64));
        mB1 = fmaxf(mB1, __shfl_xor(mB1, 32, 64));
        const float mA = hiHalf ? mA1 : mA0;   // = hsel'/sgn for channel=lane
        const float mB = hiHalf ? mB1 : mB0;

        hsel[(size_t)nA * OC + c] = sgn * mA;
        hsel[(size_t)nB * OC + c] = sgn * mB;

        // stats (fp32, unchanged)
        {
            const float ssum = fmaf(SA3, w2[3], fmaf(SA2, w2[2], fmaf(SA1, w2[1], SA0 * w2[0])));
            const float fb = fcA * biasA;
            accS = fmaf(sgn, ssum + fb, accS);
            accQ += fmaf(fb, biasA, (biasA + biasA) * ssum);
        }
        {
            const float ssum = fmaf(SB3, w2[3], fmaf(SB2, w2[2], fmaf(SB1, w2[1], SB0 * w2[0])));
            const float fb = fcB * biasB;
            accS = fmaf(sgn, ssum + fb, accS);
            accQ += fmaf(fb, biasB, (biasB + biasB) * ssum);
        }
        curv = nxtv;
    }

    // ---- final block reduction -> coalesced partials store (NO atomics)
    sred[wid][c]      = accS;
    sred[wid][64 + c] = accQ;
    g0 = red32(g0); g0 += __shfl_xor(g0, 32, 64);
    g1 = red32(g1); g1 += __shfl_xor(g1, 32, 64);
    g2 = red32(g2); g2 += __shfl_xor(g2, 32, 64);
    g3 = red32(g3); g3 += __shfl_xor(g3, 32, 64);
    g4 = red32(g4); g4 += __shfl_xor(g4, 32, 64);
    g5 = red32(g5); g5 += __shfl_xor(g5, 32, 64);
    g6 = red32(g6); g6 += __shfl_xor(g6, 32, 64);
    g7 = red32(g7); g7 += __shfl_xor(g7, 32, 64);
    g8 = red32(g8); g8 += __shfl_xor(g8, 32, 64);
    g9 = red32(g9); g9 += __shfl_xor(g9, 32, 64);
    if (lane == 0) {
        sredG[wid][0] = g0; sredG[wid][1] = g1; sredG[wid][2] = g2;
        sredG[wid][3] = g3; sredG[wid][4] = g4; sredG[wid][5] = g5;
        sredG[wid][6] = g6; sredG[wid][7] = g7; sredG[wid][8] = g8;
        sredG[wid][9] = g9;
    }
    __syncthreads();
    if (wid == 0) {
        float* row = partials + (size_t)blockIdx.x * PSTRIDE;
        row[lane]      = sred[0][lane] + sred[1][lane] + sred[2][lane] + sred[3][lane];
        row[64 + lane] = sred[0][64+lane] + sred[1][64+lane] + sred[2][64+lane] + sred[3][64+lane];
        if (lane < 10)
            row[128 + lane] = sredG[0][lane] + sredG[1][lane] + sredG[2][lane] + sredG[3][lane];
        if (lane >= 10 && lane < 16) row[128 + lane] = 0.0f;
    }
}

// ---------------------------------------------------------------------------
// Reduce stage 1: 64 blocks; block g sums rows {g, g+64, ...} of partials.
// ---------------------------------------------------------------------------
__global__ __launch_bounds__(256) void sap_reduce1(const float* __restrict__ partials,
                                                   float* __restrict__ partials2,
                                                   const int nrows)
{
    const int col = threadIdx.x;
    if (col >= PSTRIDE) return;
    const int g = blockIdx.x;                       // 0..63
    float s = 0.0f;
    for (int b = g; b < nrows; b += 64)
        s += partials[(size_t)b * PSTRIDE + col];
    partials2[(size_t)g * PSTRIDE + col] = s;
}

// ---------------------------------------------------------------------------
// Reduce stage 2 + finalize: sum 64 rows, fp64 BN stats -> scsh.
// ---------------------------------------------------------------------------
__global__ void sap_finalize(const float* __restrict__ partials2,
                             const float* __restrict__ W,
                             const float* __restrict__ gamma,
                             const float* __restrict__ beta,
                             float* __restrict__ scsh)
{
    __shared__ float stats[PSTRIDE];
    const int tid = threadIdx.x;          // 256
    if (tid < PSTRIDE) {
        float s = 0.0f;
        #pragma unroll
        for (int b = 0; b < 64; ++b)
            s += partials2[(size_t)b * PSTRIDE + tid];
        stats[tid] = s;
    }
    __syncthreads();
    if (tid >= 64) return;
    const int c = tid;
    double G[10];
    #pragma unroll
    for (int k = 0; k < 10; ++k) G[k] = (double)stats[128 + k];
    double w[4];
    w[3] = (double)W[3 * OC + c];
    #pragma unroll
    for (int k = 0; k < 3; ++k)
        w[k] = (double)W[k * OC + c] + (double)W[(4 + k) * OC + c] + (double)W[(7 + k) * OC + c];
    const double q = w[0]*w[0]*G[0] + w[1]*w[1]*G[1] + w[2]*w[2]*G[2] + w[3]*w[3]*G[3]
        + 2.0 * (w[0]*w[1]*G[4] + w[0]*w[2]*G[5] + w[0]*w[3]*G[6]
               + w[1]*w[2]*G[7] + w[1]*w[3]*G[8] + w[2]*w[3]*G[9]);
    const double S  = (double)stats[c];
    const double Qb = (double)stats[64 + c];
    const double mu_d  = S / MTOT;
    const double var_d = (q + Qb) / MTOT - mu_d * mu_d;
    const float sc = gamma[c] * rsqrtf((float)var_d + BNEPS);
    scsh[c]      = sc;
    scsh[64 + c] = beta[c] - (float)mu_d * sc;
}

// ---------------------------------------------------------------------------
// Pass 2: in-place over d_out: out = relu(scale * hsel + shift).
// ---------------------------------------------------------------------------
__global__ __launch_bounds__(256) void sap_pass2(const float* __restrict__ scsh,
                                                 float* __restrict__ out)
{
    const int idx = blockIdx.x * 256 + threadIdx.x;
    if (idx >= (NP * OC) / 4) return;
    float4 h = reinterpret_cast<float4*>(out)[idx];
    const int ci = idx & 15;
    const float4 sc = reinterpret_cast<const float4*>(scsh)[ci];
    const float4 sh = reinterpret_cast<const float4*>(scsh + 64)[ci];
    float4 o;
    o.x = fmaxf(fmaf(h.x, sc.x, sh.x), 0.0f);
    o.y = fmaxf(fmaf(h.y, sc.y, sh.y), 0.0f);
    o.z = fmaxf(fmaf(h.z, sc.z, sh.z), 0.0f);
    o.w = fmaxf(fmaf(h.w, sc.w, sh.w), 0.0f);
    reinterpret_cast<float4*>(out)[idx] = o;
}

extern "C" void kernel_launch(void* const* d_in, const int* in_sizes, int n_in,
                              void* d_out, int out_size, void* d_ws, size_t ws_size,
                              hipStream_t stream) {
    const float* feat  = (const float*)d_in[0];
    const float* W     = (const float*)d_in[1];
    const float* gamma = (const float*)d_in[2];
    const float* beta  = (const float*)d_in[3];
    const int*   nump  = (const int*)d_in[4];
    const int*   coors = (const int*)d_in[5];
    float* out = (float*)d_out;

    // pick grid1 to fit partials in d_ws (deterministic given fixed ws_size)
    int grid1 = 2048;
    const size_t fixed = 64 * PSTRIDE * 4 + 512;   // partials2 + scsh
    while (grid1 > 256 && (size_t)grid1 * PSTRIDE * 4 + fixed > ws_size)
        grid1 >>= 1;

    float* partials  = (float*)d_ws;                                   // grid1*144*4
    float* partials2 = partials + (size_t)grid1 * PSTRIDE;             // 64*144*4
    float* scsh      = partials2 + 64 * PSTRIDE;                       // 512 B

    sap_pass1<<<grid1, 256, 0, stream>>>(
        feat, W, gamma, nump, coors, out, partials, grid1 * 4);
    sap_reduce1<<<64, 256, 0, stream>>>(partials, partials2, grid1);
    sap_finalize<<<1, 256, 0, stream>>>(partials2, W, gamma, beta, scsh);
    sap_pass2<<<(NP * OC / 4 + 255) / 256, 256, 0, stream>>>(scsh, out);
}